// Round 1
// 399.531 us; speedup vs baseline: 1.0268x; 1.0268x over previous
//
#include <hip/hip_runtime.h>
#include <hip/hip_bf16.h>
#include <cstdint>
#include <cstddef>

// MultiHeadAttention B=4, S=2048, D=1024, H=16, dk=64. fp32 in/out, bf16 MFMA internals.
// cvt fp32->bf16 -> fused QKV gemm (V written transposed [B,H,dk,S]) -> flash attn (DMA-staged,
// double-buffered K/V + defer-max + setprio) -> out proj.

#define BATCH   4
#define SEQ     2048
#define D_MODEL 1024
#define NHEADS  16
#define DK      64

typedef __attribute__((ext_vector_type(8))) __bf16 bf16x8_t;
typedef __attribute__((ext_vector_type(4))) float  f32x4;

// HW packed fp32->bf16 (v_cvt_pk_bf16_f32 on gfx950)
__device__ inline unsigned int pack2(float lo, float hi) {
  __hip_bfloat162 h = __float22bfloat162_rn(make_float2(lo, hi));
  union { __hip_bfloat162 h; unsigned int u; } c; c.h = h; return c.u;
}
__device__ inline unsigned short f2bf(float f) { return (unsigned short)pack2(f, f); }

#if __has_builtin(__builtin_amdgcn_exp2f)
__device__ inline float fexp2(float x) { return __builtin_amdgcn_exp2f(x); }
#else
__device__ inline float fexp2(float x) { return __expf(x * 0.6931471805599453f); }
#endif

__device__ inline void cvt8(const float* __restrict__ s, unsigned short* __restrict__ d) {
  const float4 a = *(const float4*)s;
  const float4 b = *(const float4*)(s + 4);
  uint4 r;
  r.x = pack2(a.x, a.y); r.y = pack2(a.z, a.w);
  r.z = pack2(b.x, b.y); r.w = pack2(b.z, b.w);
  *(uint4*)d = r;
}

// async global->LDS, 16B/lane; LDS dest = wave-uniform base + lane*16B
typedef __attribute__((address_space(3))) unsigned int lds_u32_t;
typedef const __attribute__((address_space(1))) unsigned int glb_u32_t;
__device__ inline void gld16(const unsigned short* g, unsigned short* l) {
  __builtin_amdgcn_global_load_lds((glb_u32_t*)(uintptr_t)g,
                                   (lds_u32_t*)(unsigned int)(uintptr_t)l, 16, 0, 0);
}

// ---------------- fp32 -> bf16 conversion ----------------
__global__ __launch_bounds__(256) void cvt3_kernel(
    const float* __restrict__ a, const float* __restrict__ b, const float* __restrict__ c,
    unsigned short* __restrict__ oa, unsigned short* __restrict__ ob, unsigned short* __restrict__ oc)
{
  const float* s = (blockIdx.y == 0) ? a : (blockIdx.y == 1) ? b : c;
  unsigned short* d = (blockIdx.y == 0) ? oa : (blockIdx.y == 1) ? ob : oc;
  const size_t i = ((size_t)blockIdx.x * 256 + threadIdx.x) * 8;
  cvt8(s + i, d + i);
}
__global__ __launch_bounds__(256) void cvt4_kernel(
    const float* __restrict__ a, const float* __restrict__ b,
    const float* __restrict__ c, const float* __restrict__ dd,
    unsigned short* __restrict__ oa, unsigned short* __restrict__ ob,
    unsigned short* __restrict__ oc, unsigned short* __restrict__ od)
{
  const float* s = (blockIdx.y == 0) ? a : (blockIdx.y == 1) ? b : (blockIdx.y == 2) ? c : dd;
  unsigned short* d = (blockIdx.y == 0) ? oa : (blockIdx.y == 1) ? ob : (blockIdx.y == 2) ? oc : od;
  const size_t i = ((size_t)blockIdx.x * 256 + threadIdx.x) * 8;
  cvt8(s + i, d + i);
}

// ---------------- shared GEMM core: acc += A[128 rows @m0] * W[128 rows @n0]^T ----------------
// m97 structure: BK=32 unpadded LDS, global_load_lds 16B, chunk^(row&3) source-side swizzle.
__device__ inline void gemm_core(const unsigned short* __restrict__ A,
                                 const unsigned short* __restrict__ W,
                                 unsigned short* a_lds, unsigned short* b_lds,
                                 int m0, int n0, f32x4 (&acc)[4][4])
{
  const int tid  = threadIdx.x;
  const int lane = tid & 63;
  const int wv   = tid >> 6;
  const int l15  = lane & 15;
  const int quad = lane >> 4;
  const int wm = (wv & 1) * 64;
  const int wn = (wv >> 1) * 64;

  const int srow = tid >> 2;
  const int sch  = (tid & 3) ^ (srow & 3);
  const unsigned short* Ap0 = A + (size_t)(m0 + srow) * D_MODEL + sch * 8;
  const unsigned short* Ap1 = Ap0 + (size_t)64 * D_MODEL;
  const unsigned short* Wp0 = W + (size_t)(n0 + srow) * D_MODEL + sch * 8;
  const unsigned short* Wp1 = Wp0 + (size_t)64 * D_MODEL;
  unsigned short* al0 = a_lds + wv * 512;
  unsigned short* al1 = a_lds + 2048 + wv * 512;
  unsigned short* bl0 = b_lds + wv * 512;
  unsigned short* bl1 = b_lds + 2048 + wv * 512;

  const int pq = (quad ^ (l15 & 3)) * 8;

  for (int k0 = 0; k0 < D_MODEL; k0 += 32) {
    __syncthreads();
    gld16(Ap0 + k0, al0);
    gld16(Ap1 + k0, al1);
    gld16(Wp0 + k0, bl0);
    gld16(Wp1 + k0, bl1);
    __syncthreads();

    bf16x8_t af[4], bfr[4];
#pragma unroll
    for (int i = 0; i < 4; ++i)
      af[i] = *(const bf16x8_t*)&a_lds[(wm + i * 16 + l15) * 32 + pq];
#pragma unroll
    for (int j = 0; j < 4; ++j)
      bfr[j] = *(const bf16x8_t*)&b_lds[(wn + j * 16 + l15) * 32 + pq];

#pragma unroll
    for (int i = 0; i < 4; ++i)
#pragma unroll
      for (int j = 0; j < 4; ++j)
        acc[i][j] = __builtin_amdgcn_mfma_f32_16x16x32_bf16(af[i], bfr[j], acc[i][j], 0, 0, 0);
  }
}

// ---------------- fused QKV projection ----------------
// grid (M/128, N/128, 3). z=0: Q (scaled log2e/8, scatter [B,H,S,dk]); z=1: K (scatter);
// z=2: V written TRANSPOSED [B,H,dk,S].
__global__ __launch_bounds__(256) void qkv_kernel(
    const unsigned short* __restrict__ qb, const unsigned short* __restrict__ kb,
    const unsigned short* __restrict__ vb,
    const unsigned short* __restrict__ wq, const unsigned short* __restrict__ wk,
    const unsigned short* __restrict__ wvp,
    const float* __restrict__ bq, const float* __restrict__ bk, const float* __restrict__ bv,
    unsigned short* __restrict__ Qws, unsigned short* __restrict__ Kws,
    unsigned short* __restrict__ Vws)
{
  __shared__ unsigned short a_lds[128 * 32];
  __shared__ unsigned short b_lds[128 * 32];

  const int z = blockIdx.z;
  const unsigned short* A = (z == 0) ? qb : (z == 1) ? kb : vb;
  const unsigned short* W = (z == 0) ? wq : (z == 1) ? wk : wvp;
  const float* bias       = (z == 0) ? bq : (z == 1) ? bk : bv;
  unsigned short* C       = (z == 0) ? Qws : (z == 1) ? Kws : Vws;
  const int m0 = blockIdx.x * 128;
  const int n0 = blockIdx.y * 128;

  f32x4 acc[4][4];
#pragma unroll
  for (int i = 0; i < 4; ++i)
#pragma unroll
    for (int j = 0; j < 4; ++j)
      acc[i][j] = (f32x4){0.f, 0.f, 0.f, 0.f};

  gemm_core(A, W, a_lds, b_lds, m0, n0, acc);

  const int tid  = threadIdx.x;
  const int lane = tid & 63;
  const int wv   = tid >> 6;
  const int l15  = lane & 15;
  const int quad = lane >> 4;
  const int wm = (wv & 1) * 64;
  const int wn = (wv >> 1) * 64;
  // C/D layout: col = lane&15, row = quad*4 + reg  [m89]
  if (z == 2) {
    // V^T: off = ((bb*H+hh)*DK+dd)*SEQ + ss; 4 consecutive ss per lane -> uint2
    for (int j = 0; j < 4; ++j) {
      const int n = n0 + wn + j * 16 + l15;
      const int hh = n >> 6, dd = n & 63;
      const float bvl = bias[n];
      for (int i = 0; i < 4; ++i) {
        const int mbase = m0 + wm + i * 16 + quad * 4;
        const int bb = mbase >> 11, ss = mbase & 2047;
        uint2 w2 = make_uint2(pack2(acc[i][j][0] + bvl, acc[i][j][1] + bvl),
                              pack2(acc[i][j][2] + bvl, acc[i][j][3] + bvl));
        *(uint2*)(C + (((size_t)bb * NHEADS + hh) * DK + dd) * SEQ + ss) = w2;
      }
    }
  } else {
    const float oscale = (z == 0) ? 0.18033688011112042f : 1.0f;  // log2(e)/8 for Q
    for (int j = 0; j < 4; ++j) {
      const int n = n0 + wn + j * 16 + l15;
      const int hh = n >> 6, dd = n & 63;
      const float bvl = bias[n];
      for (int i = 0; i < 4; ++i) {
        const int mbase = m0 + wm + i * 16 + quad * 4;
        const int bb = mbase >> 11, ss = mbase & 2047;
        unsigned short* dst = C + (((size_t)bb * NHEADS + hh) * SEQ + ss) * DK + dd;
        for (int r = 0; r < 4; ++r)
          dst[(size_t)r * DK] = f2bf((acc[i][j][r] + bvl) * oscale);
      }
    }
  }
}

// ---------------- output projection (bf16 A, fp32 out) ----------------
__global__ __launch_bounds__(256) void outproj_kernel(
    const unsigned short* __restrict__ A, const unsigned short* __restrict__ W,
    const float* __restrict__ bias, float* __restrict__ C)
{
  __shared__ unsigned short a_lds[128 * 32];
  __shared__ unsigned short b_lds[128 * 32];
  const int m0 = blockIdx.x * 128;
  const int n0 = blockIdx.y * 128;

  f32x4 acc[4][4];
#pragma unroll
  for (int i = 0; i < 4; ++i)
#pragma unroll
    for (int j = 0; j < 4; ++j)
      acc[i][j] = (f32x4){0.f, 0.f, 0.f, 0.f};

  gemm_core(A, W, a_lds, b_lds, m0, n0, acc);

  const int tid  = threadIdx.x;
  const int lane = tid & 63;
  const int wv   = tid >> 6;
  const int l15  = lane & 15;
  const int quad = lane >> 4;
  const int wm = (wv & 1) * 64;
  const int wn = (wv >> 1) * 64;
  for (int j = 0; j < 4; ++j) {
    const int n = n0 + wn + j * 16 + l15;
    const float bvl = bias[n];
    for (int i = 0; i < 4; ++i) {
      const int mbase = m0 + wm + i * 16 + quad * 4;
      for (int r = 0; r < 4; ++r)
        C[(size_t)(mbase + r) * D_MODEL + n] = acc[i][j][r] + bvl;
    }
  }
}

// ---------------- Flash attention, S^T form, double-buffered DMA-staged K and V^T ----------------
// grid (B*H, S/64), 256 thr. Wave wv owns q-rows q0+wv*16+l15.
// S^T = K*Q^T; per-lane softmax (base-2; Q pre-scaled by log2e/8, defer-max THR=8);
// O^T = V^T*P^T. LDS tiles stride 64, source-side XOR swizzle chunk^(row&7)^(row>>3).
// 2-phase pipeline: issue next tile's gld16 before compute, ONE barrier/iter (vmcnt drains in it).
__global__ __launch_bounds__(256) void attn_kernel(
    const unsigned short* __restrict__ Q,    // [B,H,S,dk]
    const unsigned short* __restrict__ K,    // [B,H,S,dk]
    const unsigned short* __restrict__ Vt,   // [B,H,dk,S]  (pre-transposed)
    unsigned short* __restrict__ Oattn)      // [B,S,D]
{
  __shared__ unsigned short k_sw[2 * 64 * 64];
  __shared__ unsigned short vt_sw[2 * 64 * 64];
  __shared__ unsigned short pt_sw[4 * 16 * 64];

  const int tid  = threadIdx.x;
  const int lane = tid & 63;
  const int wv   = tid >> 6;
  const int l15  = lane & 15;
  const int quad = lane >> 4;
  const int bh   = blockIdx.x;            // bh-major: XCD = bh%8 -> K/V L2 locality
  const int q0   = blockIdx.y * 64;
  const size_t hoff = (size_t)bh * SEQ * DK;
  const unsigned short* Qh  = Q  + hoff;
  const unsigned short* Kh  = K  + hoff;
  const unsigned short* Vth = Vt + hoff;

  bf16x8_t qf0, qf1;
  {
    const unsigned short* qr = Qh + (size_t)(q0 + wv * 16 + l15) * DK;
    qf0 = *(const bf16x8_t*)(qr + quad * 8);
    qf1 = *(const bf16x8_t*)(qr + 32 + quad * 8);
  }

  f32x4 o[4];
#pragma unroll
  for (int t = 0; t < 4; ++t) o[t] = (f32x4){0.f, 0.f, 0.f, 0.f};
  float mval = -1e30f, lval = 0.f;

  // DMA staging: wave wv covers tile rows [wv*16, wv*16+16) in two 8-row calls.
  const int sr = lane >> 3;               // 0..7
  const int pc = lane & 7;                // phys chunk
  const int r0 = wv * 16 + sr;
  const int r1 = r0 + 8;
  const int sem0 = pc ^ (r0 & 7) ^ (r0 >> 3);
  const int sem1 = pc ^ (r1 & 7) ^ (r1 >> 3);
  const unsigned short* KsA = Kh  + (size_t)r0 * DK  + sem0 * 8;   // + key0*DK per iter
  const unsigned short* KsB = Kh  + (size_t)r1 * DK  + sem1 * 8;
  const unsigned short* VsA = Vth + (size_t)r0 * SEQ + sem0 * 8;   // + key0 per iter
  const unsigned short* VsB = Vth + (size_t)r1 * SEQ + sem1 * 8;
  unsigned short* kd = k_sw  + wv * 1024;
  unsigned short* vd = vt_sw + wv * 1024;

#define STAGE(buf, key0) do {                                        \
    gld16(KsA + (size_t)(key0) * DK, kd + (buf) * 4096);             \
    gld16(KsB + (size_t)(key0) * DK, kd + (buf) * 4096 + 512);       \
    gld16(VsA + (key0),              vd + (buf) * 4096);             \
    gld16(VsB + (key0),              vd + (buf) * 4096 + 512);       \
  } while (0)

  const int swz_l15 = (l15 & 7) ^ (l15 >> 3);
  unsigned short* pt_base = pt_sw + wv * 1024;

  // prologue: stage tile 0 into buffer 0
  STAGE(0, 0);
  __syncthreads();                         // drains vmcnt(0): tile 0 resident

  int cur = 0;
  for (int kb = 0; kb < SEQ / 64; ++kb) {
    // issue next tile's loads FIRST so they overlap this tile's compute
    if (kb + 1 < SEQ / 64) STAGE(cur ^ 1, (kb + 1) * 64);

    const unsigned short* kcur = k_sw  + cur * 4096;
    const unsigned short* vcur = vt_sw + cur * 4096;

    // S^T = K·Q^T
    f32x4 s[4];
    __builtin_amdgcn_s_setprio(1);
#pragma unroll
    for (int t = 0; t < 4; ++t) {
      const int row = t * 16 + l15;
      const int sw  = (row & 7) ^ (row >> 3);
      bf16x8_t kf0 = *(const bf16x8_t*)&kcur[row * 64 + ((quad ^ sw) << 3)];
      bf16x8_t kf1 = *(const bf16x8_t*)&kcur[row * 64 + (((quad | 4) ^ sw) << 3)];
      f32x4 z = (f32x4){0.f, 0.f, 0.f, 0.f};
      z = __builtin_amdgcn_mfma_f32_16x16x32_bf16(kf0, qf0, z, 0, 0, 0);
      z = __builtin_amdgcn_mfma_f32_16x16x32_bf16(kf1, qf1, z, 0, 0, 0);
      s[t] = z;
    }
    __builtin_amdgcn_s_setprio(0);

    // online softmax, base-2 (scale folded into Q), defer-max (T13, THR=8 => P <= 2^8)
    float mx = s[0][0];
#pragma unroll
    for (int t = 0; t < 4; ++t)
#pragma unroll
      for (int r = 0; r < 4; ++r) mx = fmaxf(mx, s[t][r]);
    mx = fmaxf(mx, __shfl_xor(mx, 16));
    mx = fmaxf(mx, __shfl_xor(mx, 32));
    if (__any(mx > mval + 8.0f)) {
      const float mnew  = fmaxf(mval, mx);
      const float alpha = fexp2(mval - mnew);
      mval = mnew;
      lval *= alpha;
#pragma unroll
      for (int t = 0; t < 4; ++t) o[t] *= alpha;
    }
    float rs = 0.f;
    float p[4][4];
#pragma unroll
    for (int t = 0; t < 4; ++t)
#pragma unroll
      for (int r = 0; r < 4; ++r) { p[t][r] = fexp2(s[t][r] - mval); rs += p[t][r]; }
    rs += __shfl_xor(rs, 16);
    rs += __shfl_xor(rs, 32);
    lval += rs;

    // P -> LDS rows [q][key], b64 packed stores (HW cvt_pk)
#pragma unroll
    for (int t = 0; t < 4; ++t) {
      const int chunk = 2 * t + (quad >> 1);
      unsigned short* dst = pt_base + l15 * 64 + ((chunk ^ swz_l15) << 3) + (quad & 1) * 4;
      *(uint2*)dst = make_uint2(pack2(p[t][0], p[t][1]), pack2(p[t][2], p[t][3]));
    }
    asm volatile("s_waitcnt lgkmcnt(0)" ::: "memory");   // same-wave write->read

    bf16x8_t pf0 = *(const bf16x8_t*)(pt_base + l15 * 64 + ((quad ^ swz_l15) << 3));
    bf16x8_t pf1 = *(const bf16x8_t*)(pt_base + l15 * 64 + (((quad | 4) ^ swz_l15) << 3));

    // O^T += V^T · P^T
    __builtin_amdgcn_s_setprio(1);
#pragma unroll
    for (int nt = 0; nt < 4; ++nt) {
      const int row = nt * 16 + l15;
      const int sw  = (row & 7) ^ (row >> 3);
      bf16x8_t vf0 = *(const bf16x8_t*)&vcur[row * 64 + ((quad ^ sw) << 3)];
      bf16x8_t vf1 = *(const bf16x8_t*)&vcur[row * 64 + (((quad | 4) ^ sw) << 3)];
      o[nt] = __builtin_amdgcn_mfma_f32_16x16x32_bf16(vf0, pf0, o[nt], 0, 0, 0);
      o[nt] = __builtin_amdgcn_mfma_f32_16x16x32_bf16(vf1, pf1, o[nt], 0, 0, 0);
    }
    __builtin_amdgcn_s_setprio(0);

    // single barrier per iter: drains this iter's prefetch (vmcnt) AND all waves' LDS reads
    __syncthreads();
    cur ^= 1;
  }
#undef STAGE

  // epilogue: lane owns q = q0+wv*16+l15, d = nt*16 + quad*4 + r
  const int bb = bh >> 4, hh = bh & 15;
  const float inv = 1.0f / lval;
  unsigned short* orow = Oattn + (size_t)(bb * SEQ + q0 + wv * 16 + l15) * D_MODEL + hh * DK + quad * 4;
#pragma unroll
  for (int nt = 0; nt < 4; ++nt) {
    f32x4 v = o[nt];
    *(uint2*)(orow + nt * 16) = make_uint2(pack2(v[0] * inv, v[1] * inv),
                                           pack2(v[2] * inv, v[3] * inv));
  }
}

extern "C" void kernel_launch(void* const* d_in, const int* in_sizes, int n_in,
                              void* d_out, int out_size, void* d_ws, size_t ws_size,
                              hipStream_t stream) {
  const float* query = (const float*)d_in[0];
  const float* key   = (const float*)d_in[1];
  const float* value = (const float*)d_in[2];
  const float* Wq    = (const float*)d_in[3];
  const float* bq    = (const float*)d_in[4];
  const float* Wk    = (const float*)d_in[5];
  const float* bk    = (const float*)d_in[6];
  const float* Wv    = (const float*)d_in[7];
  const float* bv    = (const float*)d_in[8];
  const float* Wo    = (const float*)d_in[9];
  const float* bo    = (const float*)d_in[10];

  const size_t E  = (size_t)BATCH * SEQ * D_MODEL;   // 8,388,608
  const size_t WE = (size_t)D_MODEL * D_MODEL;       // 1,048,576
  unsigned short* ws  = (unsigned short*)d_ws;
  unsigned short* Qws = ws;                          // [B,H,S,dk], pre-scaled log2e/8
  unsigned short* Kws = ws + E;
  unsigned short* Vws = ws + 2 * E;                  // [B,H,dk,S] transposed
  unsigned short* qb  = ws + 3 * E;
  unsigned short* kb  = ws + 4 * E;
  unsigned short* vb  = ws + 5 * E;
  unsigned short* wqb = ws + 6 * E;
  unsigned short* wkb = wqb + WE;
  unsigned short* wvb = wqb + 2 * WE;
  unsigned short* wob = wqb + 3 * WE;
  unsigned short* Aws = qb;                          // alias: qb dead after QKV GEMM

  cvt3_kernel<<<dim3(E / 2048, 3), 256, 0, stream>>>(query, key, value, qb, kb, vb);
  cvt4_kernel<<<dim3(WE / 2048, 4), 256, 0, stream>>>(Wq, Wk, Wv, Wo, wqb, wkb, wvb, wob);

  qkv_kernel<<<dim3(BATCH * SEQ / 128, D_MODEL / 128, 3), 256, 0, stream>>>(
      qb, kb, vb, wqb, wkb, wvb, bq, bk, bv, Qws, Kws, Vws);
  attn_kernel<<<dim3(BATCH * NHEADS, SEQ / 64), 256, 0, stream>>>(Qws, Kws, Vws, Aws);
  outproj_kernel<<<dim3(BATCH * SEQ / 128, D_MODEL / 128), 256, 0, stream>>>(
      Aws, wob, bo, (float*)d_out);
}